// Round 1
// baseline (176.512 us; speedup 1.0000x reference)
//
#include <hip/hip_runtime.h>

// QuantileLoss: mean over [ (p0-t0)^2, (p1-t1)^2, (p2-t2)^2, lower, upper ]
//   lower = p3>p2 ? (p4-t2)*4 : (p3>0.95*t2 ? 0 : (p3-0.95*t2)^2)
//   upper = p4<p2 ? (p4-t2)*4 : (p4<1.05*t2 ? 0 : (p4-1.05*t2)^2)
// Memory-bound: 128 MiB read -> ~21 us floor at 6.3 TB/s.

#define BLOCK 256
#define ROWS_PER_THREAD 4

__device__ __forceinline__ float row_loss(float p0, float p1, float p2,
                                          float p3, float p4,
                                          float t0, float t1, float t2) {
    float d0 = p0 - t0, d1 = p1 - t1, d2 = p2 - t2;
    float acc = d0 * d0 + d1 * d1 + d2 * d2;
    float tl = t2 * 0.95f;
    float tu = t2 * 1.05f;
    float pen = (p4 - t2) * 4.0f;
    float dl = p3 - tl;
    float du = p4 - tu;
    float lower = (p3 > p2) ? pen : ((p3 > tl) ? 0.0f : dl * dl);
    float upper = (p4 < p2) ? pen : ((p4 < tu) ? 0.0f : du * du);
    return acc + lower + upper;
}

__global__ __launch_bounds__(BLOCK) void ql_main(const float* __restrict__ preds,
                                                 const float* __restrict__ target,
                                                 double* __restrict__ ws,
                                                 int rows) {
    long tid = (long)blockIdx.x * BLOCK + threadIdx.x;
    long r0 = tid * ROWS_PER_THREAD;
    float acc = 0.0f;

    if (r0 + ROWS_PER_THREAD - 1 < rows) {
        // fast path: 4 rows -> 20 pred floats (5 x float4), 12 target floats (3 x float4)
        const float4* pp = (const float4*)(preds + r0 * 5);
        const float4* tp = (const float4*)(target + r0 * 3);
        union { float4 v[5]; float f[20]; } P;
        union { float4 v[3]; float f[12]; } T;
        P.v[0] = pp[0]; P.v[1] = pp[1]; P.v[2] = pp[2]; P.v[3] = pp[3]; P.v[4] = pp[4];
        T.v[0] = tp[0]; T.v[1] = tp[1]; T.v[2] = tp[2];
#pragma unroll
        for (int j = 0; j < ROWS_PER_THREAD; ++j) {
            acc += row_loss(P.f[5 * j + 0], P.f[5 * j + 1], P.f[5 * j + 2],
                            P.f[5 * j + 3], P.f[5 * j + 4],
                            T.f[3 * j + 0], T.f[3 * j + 1], T.f[3 * j + 2]);
        }
    } else {
        // tail: scalar per-row
        for (long r = r0; r < rows && r < r0 + ROWS_PER_THREAD; ++r) {
            const float* p = preds + r * 5;
            const float* t = target + r * 3;
            acc += row_loss(p[0], p[1], p[2], p[3], p[4], t[0], t[1], t[2]);
        }
    }

    // wave (64-lane) reduction in double
    double dacc = (double)acc;
#pragma unroll
    for (int off = 32; off > 0; off >>= 1)
        dacc += __shfl_down(dacc, off, 64);

    __shared__ double wsum[BLOCK / 64];
    int lane = threadIdx.x & 63;
    int wave = threadIdx.x >> 6;
    if (lane == 0) wsum[wave] = dacc;
    __syncthreads();

    if (threadIdx.x == 0) {
        double b = 0.0;
#pragma unroll
        for (int w = 0; w < BLOCK / 64; ++w) b += wsum[w];
        atomicAdd(ws, b);  // device-scope by default on CDNA
    }
}

__global__ void ql_finalize(const double* __restrict__ ws, float* __restrict__ out, long rows) {
    out[0] = (float)(ws[0] / (double)(rows * 5));
}

extern "C" void kernel_launch(void* const* d_in, const int* in_sizes, int n_in,
                              void* d_out, int out_size, void* d_ws, size_t ws_size,
                              hipStream_t stream) {
    const float* preds = (const float*)d_in[0];
    const float* target = (const float*)d_in[1];
    long rows = (long)in_sizes[0] / 5;

    double* acc = (double*)d_ws;
    hipMemsetAsync(acc, 0, sizeof(double), stream);

    long threads_needed = (rows + ROWS_PER_THREAD - 1) / ROWS_PER_THREAD;
    int blocks = (int)((threads_needed + BLOCK - 1) / BLOCK);

    ql_main<<<blocks, BLOCK, 0, stream>>>(preds, target, acc, (int)rows);
    ql_finalize<<<1, 1, 0, stream>>>(acc, (float*)d_out, rows);
}